// Round 11
// baseline (150.612 us; speedup 1.0000x reference)
//
#include <hip/hip_runtime.h>
#include <cfloat>

typedef unsigned long long u64;

#define CDESC 32
#define N0 4096
#define N1 512

// sign-transformed float bits: monotone u32 over the float total order
__device__ __forceinline__ unsigned fbits_mono(float d) {
    unsigned b = __float_as_uint(d);
    return (d >= 0.f) ? (b | 0x80000000u) : ~b;
}

__device__ __forceinline__ void wave_reduce_atomic(float v, float* acc) {
#pragma unroll
    for (int off = 32; off > 0; off >>= 1) v += __shfl_down(v, off, 64);
    if ((threadIdx.x & 63) == 0) atomicAdd(acc, v);
}

__device__ __forceinline__ float rl(float v, int j) {   // wave-broadcast lane j
    return __int_as_float(__builtin_amdgcn_readlane(__float_as_int(v), j));
}

// ---------------- pass-1 body: x-filter (bit-exact since R1) ----------------
template<int S, int R>
__device__ __forceinline__ void pass1_body(const float* __restrict__ in,
                                           float* __restrict__ out, int idx) {
    int xo = idx & (S - 1);
    int r  = idx / S;
    int y  = r & 63; r >>= 6;
    int z  = r & 63; r >>= 6;
    int bc = r;                                    // 0..11
    const float* row = in + (((bc * 64) + z) * 64 + y) * 64;
    constexpr int KW = 2 * R;
    int j0 = R * xo - R / 2;
    float sum = 0.f, wsum = 0.f;
#pragma unroll
    for (int t = 0; t < KW; ++t) {
        int j = j0 + t;
        float w = 1.f - fabsf((float)t - ((float)R - 0.5f)) / (float)R;
        if (j >= 0 && j < 64) { sum = fmaf(w, row[j], sum); wsum += w; }
    }
    out[idx] = sum / wsum;
}

// K1: x-filter (blocks 0..4607) + descriptor transpose to point-major
// (blocks 4608..4895) + init acc. blockIdx.y = side (src/tgt).
__global__ __launch_bounds__(256) void pass1_both(
        const float* __restrict__ csrc, const float* __restrict__ ctgt,
        const float* __restrict__ sd0, const float* __restrict__ td0,
        const float* __restrict__ sd1, const float* __restrict__ td1,
        float* __restrict__ t16a, float* __restrict__ t16b,
        float* __restrict__ t8a,  float* __restrict__ t8b,
        float* __restrict__ sd0T, float* __restrict__ td0T,
        float* __restrict__ sd1T, float* __restrict__ td1T,
        float* __restrict__ acc) {
    __shared__ float tile[64 * 33];                // transpose tile (+1 pad)
    const int tid = threadIdx.x;
    const int bx  = blockIdx.x, by = blockIdx.y;
    if (by == 0 && bx == 0 && tid < 4) acc[tid] = 0.f;
    if (bx < 3072) {
        pass1_body<16, 4>(by ? ctgt : csrc, by ? t16b : t16a, bx * 256 + tid);
    } else if (bx < 4608) {
        pass1_body<8, 8>(by ? ctgt : csrc, by ? t8b : t8a, (bx - 3072) * 256 + tid);
    } else {
        // ---- transpose [b][32][N] -> [b][N][32], 64-point tiles ----
        int tl = bx - 4608;                        // 0..287
        const float* din; float* dout; int N, b, n0;
        if (tl < 256) { din = by ? td0 : sd0; dout = by ? td0T : sd0T;
                        N = N0; b = tl >> 6; n0 = (tl & 63) * 64; }
        else { tl -= 256; din = by ? td1 : sd1; dout = by ? td1T : sd1T;
               N = N1; b = tl >> 3; n0 = (tl & 7) * 64; }
#pragma unroll
        for (int i = 0; i < 8; ++i) {              // load: coalesced 64-float rows
            int idx = tid + i * 256;
            int c = idx >> 6, j = idx & 63;
            tile[j * 33 + c] = din[((size_t)b * CDESC + c) * N + n0 + j];
        }
        __syncthreads();
#pragma unroll
        for (int i = 0; i < 8; ++i) {              // store: contiguous 32-float points
            int idx = tid + i * 256;
            int p = idx >> 5, c = idx & 31;
            dout[((size_t)b * N + n0 + p) * CDESC + c] = tile[p * 33 + c];
        }
    }
}

// K2: both stages' y/z-filter, 8 sub-threads per point (verified R6/R7).
__global__ __launch_bounds__(256) void pass2_both(
        const float* __restrict__ t16a, const float* __restrict__ t16b,
        const float* __restrict__ t8a,  const float* __restrict__ t8b,
        float4* __restrict__ ps0, float4* __restrict__ pt0,
        float4* __restrict__ ps1, float4* __restrict__ pt1) {
    int gid = blockIdx.x * 256 + threadIdx.x;
    if (blockIdx.x < 1024) {
        int sub = gid & 7, p = gid >> 3;
        int side = p >> 14, r = p & 16383;
        int b = r >> 12, n = r & 4095;
        int x = n & 15, y = (n >> 4) & 15, z = n >> 8;
        const float* t = side ? t16b : t16a;
        float wy[8]; int jy[8];
        float wys = 0.f, wzs = 0.f;
#pragma unroll
        for (int tt = 0; tt < 8; ++tt) {
            float w = 1.f - fabsf((float)tt - 3.5f) * 0.25f;
            int j = 4 * y - 2 + tt;
            bool v = (unsigned)j < 64u;
            wy[tt] = v ? w : 0.f; jy[tt] = v ? j : 0; wys += wy[tt];
            int jz = 4 * z - 2 + tt;
            if ((unsigned)jz < 64u) wzs += w;
        }
        float a0 = 0.f, a1 = 0.f, a2 = 0.f;
        {
            float wz = 1.f - fabsf((float)sub - 3.5f) * 0.25f;
            int jz = 4 * z - 2 + sub;
            if ((unsigned)jz < 64u) {
                const float* bz = t + (size_t)b * 196608 + jz * 1024 + x;
#pragma unroll
                for (int ty = 0; ty < 8; ++ty) {
                    float w = wz * wy[ty];
                    const float* pr = bz + jy[ty] * 16;
                    a0 = fmaf(w, pr[0],      a0);
                    a1 = fmaf(w, pr[65536],  a1);
                    a2 = fmaf(w, pr[131072], a2);
                }
            }
        }
#pragma unroll
        for (int m = 1; m < 8; m <<= 1) {
            a0 += __shfl_xor(a0, m, 64);
            a1 += __shfl_xor(a1, m, 64);
            a2 += __shfl_xor(a2, m, 64);
        }
        if (sub == 0) {
            float inv = 1.f / (wys * wzs);
            a0 *= inv; a1 *= inv; a2 *= inv;
            float4* pts = side ? pt0 : ps0;
            pts[b * N0 + n] = make_float4(a0, a1, a2, a0 * a0 + a1 * a1 + a2 * a2);
        }
    } else {
        int g = gid - 262144;
        int sub = g & 7, p = g >> 3;
        int side = p >> 11, r = p & 2047;
        int b = r >> 9, n = r & 511;
        int x = n & 7, y = (n >> 3) & 7, z = n >> 6;
        const float* t = side ? t8b : t8a;
        constexpr int CS = 64 * 64 * 8;
        float wy[16]; int jy[16];
        float wys = 0.f, wzs = 0.f;
#pragma unroll
        for (int tt = 0; tt < 16; ++tt) {
            float w = 1.f - fabsf((float)tt - 7.5f) * 0.125f;
            int j = 8 * y - 4 + tt;
            bool v = (unsigned)j < 64u;
            wy[tt] = v ? w : 0.f; jy[tt] = v ? j : 0; wys += wy[tt];
            int jz = 8 * z - 4 + tt;
            if ((unsigned)jz < 64u) wzs += w;
        }
        float a0 = 0.f, a1 = 0.f, a2 = 0.f;
#pragma unroll
        for (int k = 0; k < 2; ++k) {
            int tt = 2 * sub + k;
            float wz = 1.f - fabsf((float)tt - 7.5f) * 0.125f;
            int jz = 8 * z - 4 + tt;
            if ((unsigned)jz < 64u) {
                const float* bz = t + b * 3 * CS + jz * (64 * 8) + x;
#pragma unroll 1
                for (int ty = 0; ty < 16; ++ty) {
                    float w = wz * wy[ty];
                    const float* pr = bz + jy[ty] * 8;
                    a0 = fmaf(w, pr[0],      a0);
                    a1 = fmaf(w, pr[CS],     a1);
                    a2 = fmaf(w, pr[2 * CS], a2);
                }
            }
        }
#pragma unroll
        for (int m = 1; m < 8; m <<= 1) {
            a0 += __shfl_xor(a0, m, 64);
            a1 += __shfl_xor(a1, m, 64);
            a2 += __shfl_xor(a2, m, 64);
        }
        if (sub == 0) {
            float inv = 1.f / (wys * wzs);
            a0 *= inv; a1 *= inv; a2 *= inv;
            float4* pts = side ? pt1 : ps1;
            pts[b * N1 + n] = make_float4(a0, a1, a2, a0 * a0 + a1 * a1 + a2 * a2);
        }
    }
}

// cosine of two point-major 32-float descriptors (coalesced float4 reads)
__device__ __forceinline__ float cos_pm(const float* __restrict__ sT,
                                        const float* __restrict__ tT,
                                        size_t si, size_t ti) {
    const float4* s = (const float4*)(sT + si * CDESC);
    const float4* t = (const float4*)(tT + ti * CDESC);
    float num = 0.f, s2 = 0.f, t2 = 0.f;
#pragma unroll
    for (int c = 0; c < 8; ++c) {
        float4 a = s[c], g = t[c];
        num = fmaf(a.x, g.x, fmaf(a.y, g.y, fmaf(a.z, g.z, fmaf(a.w, g.w, num))));
        s2  = fmaf(a.x, a.x, fmaf(a.y, a.y, fmaf(a.z, a.z, fmaf(a.w, a.w, s2))));
        t2  = fmaf(g.x, g.x, fmaf(g.y, g.y, fmaf(g.z, g.z, fmaf(g.w, g.w, t2))));
    }
    return num / (fmaxf(sqrtf(s2), 1e-8f) * fmaxf(sqrtf(t2), 1e-8f));
}

// readlane-broadcast scan with 4 INDEPENDENT best-chains (j mod 4) for ILP at
// 1 wave/SIMD. Each chain: strict <, ascending j-within-tile (inline-const
// cndmask), ascending tiles -> per-chain first-min. Final combine = min of 4
// packed (mono(d)<<32|m) keys == global lexicographic (d,m) min == jnp.argmin
// first-min. Distances use the same fma order as R10 (bit-identical).
template<int NTILES>
__device__ __forceinline__ u64 rl_scan4(const float4* __restrict__ tq, int lane,
                                        float Px, float Py, float Pz) {
    float4 Qc = tq[lane];
    float b0 = FLT_MAX, b1 = FLT_MAX, b2 = FLT_MAX, b3 = FLT_MAX;
    int   m0 = 0, m1 = 0, m2 = 0, m3 = 0;
#pragma unroll 1
    for (int t = 0; t < NTILES; ++t) {
        float4 Qn = tq[((t + 1) & (NTILES - 1)) * 64 + lane];   // prefetch
        float t0 = FLT_MAX, t1 = FLT_MAX, t2 = FLT_MAX, t3 = FLT_MAX;
        int   j0 = 0, j1 = 0, j2 = 0, j3 = 0;
#pragma unroll
        for (int j = 0; j < 64; j += 4) {
            float d0 = fmaf(Px, rl(Qc.x, j + 0), fmaf(Py, rl(Qc.y, j + 0),
                       fmaf(Pz, rl(Qc.z, j + 0), rl(Qc.w, j + 0))));
            float d1 = fmaf(Px, rl(Qc.x, j + 1), fmaf(Py, rl(Qc.y, j + 1),
                       fmaf(Pz, rl(Qc.z, j + 1), rl(Qc.w, j + 1))));
            float d2 = fmaf(Px, rl(Qc.x, j + 2), fmaf(Py, rl(Qc.y, j + 2),
                       fmaf(Pz, rl(Qc.z, j + 2), rl(Qc.w, j + 2))));
            float d3 = fmaf(Px, rl(Qc.x, j + 3), fmaf(Py, rl(Qc.y, j + 3),
                       fmaf(Pz, rl(Qc.z, j + 3), rl(Qc.w, j + 3))));
            if (d0 < t0) { t0 = d0; j0 = j + 0; }  // inline-const cndmask
            if (d1 < t1) { t1 = d1; j1 = j + 1; }
            if (d2 < t2) { t2 = d2; j2 = j + 2; }
            if (d3 < t3) { t3 = d3; j3 = j + 3; }
        }
        int base = t * 64;
        if (t0 < b0) { b0 = t0; m0 = base + j0; }
        if (t1 < b1) { b1 = t1; m1 = base + j1; }
        if (t2 < b2) { b2 = t2; m2 = base + j2; }
        if (t3 < b3) { b3 = t3; m3 = base + j3; }
        Qc = Qn;
    }
    u64 k0 = ((u64)fbits_mono(b0) << 32) | (unsigned)m0;
    u64 k1 = ((u64)fbits_mono(b1) << 32) | (unsigned)m1;
    u64 k2 = ((u64)fbits_mono(b2) << 32) | (unsigned)m2;
    u64 k3 = ((u64)fbits_mono(b3) << 32) | (unsigned)m3;
    u64 ka = k0 < k1 ? k0 : k1;
    u64 kb = k2 < k3 ? k2 : k3;
    return ka < kb ? ka : kb;
}

// ======================= K3: argmin + cosine, 4-chain readlane scan =======================
// blocks 0..255: stage-0, block = (b, 64-src tile); 4 waves split m 4x1024.
//   Cross-wave combine via packed-key min in LDS. Wave 0 does the point-major
//   coalesced cosine. blocks 256..263: stage-1. 264-ticket finalizes out.
__global__ __launch_bounds__(256) void nn_cos_all(
        const float4* __restrict__ ps0, const float4* __restrict__ pt0,
        const float* __restrict__ sd0T, const float* __restrict__ td0T,
        const float4* __restrict__ ps1, const float4* __restrict__ pt1,
        const float* __restrict__ sd1T, const float* __restrict__ td1T,
        float* acc, float* __restrict__ out) {
    __shared__ u64 keys[256];
    const int tid = threadIdx.x;
    const int bx  = blockIdx.x;
    const int w = tid >> 6, lane = tid & 63;

    if (bx < 256) {
        int b = bx >> 6, stile = bx & 63;
        int n = stile * 64 + lane;
        float4 P = ps0[b * N0 + n];
        u64 key = rl_scan4<16>(pt0 + b * N0 + w * 1024, lane,
                               -2.f * P.x, -2.f * P.y, -2.f * P.z);
        keys[tid] = key + ((u64)(w * 1024));       // fold window offset into m
        __syncthreads();
        if (tid < 64) {
            u64 k0 = keys[tid],       k1 = keys[tid + 64];
            u64 k2 = keys[tid + 128], k3 = keys[tid + 192];
            u64 ka = k0 < k1 ? k0 : k1;
            u64 kb = k2 < k3 ? k2 : k3;
            u64 kk = ka < kb ? ka : kb;            // m in low bits: first-min on ties
            int nearest = (int)(unsigned)(kk & 0xFFFFFFFFull);
            int n2 = stile * 64 + tid;
            float cosv = cos_pm(sd0T, td0T, (size_t)b * N0 + n2,
                                (size_t)b * N0 + nearest);
            wave_reduce_atomic(cosv, acc + 0);
        }
    } else {
        int bb = bx - 256;
        int b = bb >> 1;
        int n = (bb & 1) * 256 + tid;
        float4 P = ps1[b * N1 + n];
        u64 key = rl_scan4<8>(pt1 + b * N1, lane,
                              -2.f * P.x, -2.f * P.y, -2.f * P.z);
        int bm = (int)(unsigned)(key & 0xFFFFFFFFull);
        float cosv = cos_pm(sd1T, td1T, (size_t)b * N1 + n, (size_t)b * N1 + bm);
        wave_reduce_atomic(cosv, acc + 1);
    }

    __syncthreads();                               // block's atomics all issued
    if (tid == 0) {
        __threadfence();
        unsigned old = atomicAdd((unsigned*)(acc + 2), 1u);
        if (old == 263u) {                         // last of 264 blocks
            float a0 = atomicAdd(acc + 0, 0.f);
            float a1 = atomicAdd(acc + 1, 0.f);
            out[0] = 1.f - 0.5f * (a0 * (1.f / 16384.f) + a1 * (1.f / 2048.f));
        }
    }
}

extern "C" void kernel_launch(void* const* d_in, const int* in_sizes, int n_in,
                              void* d_out, int out_size, void* d_ws, size_t ws_size,
                              hipStream_t stream) {
    const float* c_src = (const float*)d_in[0];   // [4,3,64,64,64]
    const float* c_tgt = (const float*)d_in[1];
    const float* sd0   = (const float*)d_in[2];   // [4,32,16,16,16]
    const float* td0   = (const float*)d_in[3];
    const float* sd1   = (const float*)d_in[4];   // [4,32,8,8,8]
    const float* td1   = (const float*)d_in[5];
    float* out = (float*)d_out;

    char* ws = (char*)d_ws;
    float* acc  = (float*)ws;                      // [0]=sum0 [1]=sum1 [2]=ticket
    float* t16a = (float*)(ws + 256);              // 786432 floats each
    float* t16b = t16a + 786432;
    float* t8a  = t16b + 786432;                   // 393216 floats each
    float* t8b  = t8a + 393216;
    float4* ps0 = (float4*)(t8b + 393216);         // 16384 float4
    float4* pt0 = ps0 + 16384;
    float4* ps1 = pt0 + 16384;                     // 2048 float4
    float4* pt1 = ps1 + 2048;
    float* sd0T = (float*)(pt1 + 2048);            // 524288 floats each
    float* td0T = sd0T + 524288;
    float* sd1T = td0T + 524288;                   // 65536 floats each
    float* td1T = sd1T + 65536;

    pass1_both<<<dim3(4896, 2), 256, 0, stream>>>(c_src, c_tgt, sd0, td0, sd1, td1,
                                                  t16a, t16b, t8a, t8b,
                                                  sd0T, td0T, sd1T, td1T, acc);
    pass2_both<<<1152, 256, 0, stream>>>(t16a, t16b, t8a, t8b, ps0, pt0, ps1, pt1);
    nn_cos_all<<<264, 256, 0, stream>>>(ps0, pt0, sd0T, td0T, ps1, pt1,
                                        sd1T, td1T, acc, out);
}

// Round 12
// 128.191 us; speedup vs baseline: 1.1749x; 1.1749x over previous
//
#include <hip/hip_runtime.h>
#include <cfloat>

typedef unsigned long long u64;

#define CDESC 32
#define N0 4096
#define N1 512

// sign-transformed float bits: monotone u32 over the float total order
__device__ __forceinline__ unsigned fbits_mono(float d) {
    unsigned b = __float_as_uint(d);
    return (d >= 0.f) ? (b | 0x80000000u) : ~b;
}

__device__ __forceinline__ void wave_reduce_atomic(float v, float* acc) {
#pragma unroll
    for (int off = 32; off > 0; off >>= 1) v += __shfl_down(v, off, 64);
    if ((threadIdx.x & 63) == 0) atomicAdd(acc, v);
}

// ======================= K1: fused x-filter (both stages) + transpose =======================
// blocks 0..767 (x2 sides): one (channel, z) input plane staged to LDS once;
// compute BOTH S=16 (R=4) and S=8 (R=8) x-filter outputs from it (input read
// once instead of twice -> -25 MB HBM). Same tap order/weights as the verified
// pass1_body (exact /4, /8) -> bit-exact.
// blocks 768..1055: descriptor transpose [b][32][N] -> [b][N][32].
__global__ __launch_bounds__(256) void pass1_fused(
        const float* __restrict__ csrc, const float* __restrict__ ctgt,
        const float* __restrict__ sd0, const float* __restrict__ td0,
        const float* __restrict__ sd1, const float* __restrict__ td1,
        float* __restrict__ t16a, float* __restrict__ t16b,
        float* __restrict__ t8a,  float* __restrict__ t8b,
        float* __restrict__ sd0T, float* __restrict__ td0T,
        float* __restrict__ sd1T, float* __restrict__ td1T,
        float* __restrict__ acc) {
    __shared__ __align__(16) float sRow[4096];     // one 64x64 plane (16 KB)
    const int tid = threadIdx.x;
    const int bx  = blockIdx.x, by = blockIdx.y;
    if (by == 0 && bx == 0 && tid < 4) acc[tid] = 0.f;

    if (bx < 768) {
        int bc = bx >> 6, z = bx & 63;             // channel-plane, z-slice
        const float* in = by ? ctgt : csrc;
        float* o16 = by ? t16b : t16a;
        float* o8  = by ? t8b  : t8a;
        const float4* src = (const float4*)(in + (size_t)(bc * 64 + z) * 4096);
        float4* dst = (float4*)sRow;
#pragma unroll
        for (int k = 0; k < 4; ++k)                // coalesced 16 KB stage
            dst[tid + k * 256] = src[tid + k * 256];
        __syncthreads();
#pragma unroll
        for (int k = 0; k < 6; ++k) {              // 1536 outputs, 6/thread
            int o = tid + k * 256;
            if (o < 1024) {                        // S=16, R=4 (k=0..3: no divergence)
                int y = o >> 4, xo = o & 15;
                int j0 = 4 * xo - 2;
                float sum = 0.f, wsum = 0.f;
#pragma unroll
                for (int t = 0; t < 8; ++t) {
                    int j = j0 + t;
                    float w = 1.f - fabsf((float)t - 3.5f) / 4.f;
                    if (j >= 0 && j < 64) { sum = fmaf(w, sRow[y * 64 + j], sum); wsum += w; }
                }
                o16[bc * 65536 + z * 1024 + y * 16 + xo] = sum / wsum;
            } else {                               // S=8, R=8 (k=4,5)
                int o2 = o - 1024;
                int y = o2 >> 3, xo = o2 & 7;
                int j0 = 8 * xo - 4;
                float sum = 0.f, wsum = 0.f;
#pragma unroll
                for (int t = 0; t < 16; ++t) {
                    int j = j0 + t;
                    float w = 1.f - fabsf((float)t - 7.5f) / 8.f;
                    if (j >= 0 && j < 64) { sum = fmaf(w, sRow[y * 64 + j], sum); wsum += w; }
                }
                o8[bc * 32768 + z * 512 + y * 8 + xo] = sum / wsum;
            }
        }
    } else {
        // ---- transpose [b][32][N] -> [b][N][32], 64-point tiles (verified R7) ----
        __shared__ float tile[64 * 33];
        int tl = bx - 768;                         // 0..287
        const float* din; float* dout; int N, b, n0;
        if (tl < 256) { din = by ? td0 : sd0; dout = by ? td0T : sd0T;
                        N = N0; b = tl >> 6; n0 = (tl & 63) * 64; }
        else { tl -= 256; din = by ? td1 : sd1; dout = by ? td1T : sd1T;
               N = N1; b = tl >> 3; n0 = (tl & 7) * 64; }
#pragma unroll
        for (int i = 0; i < 8; ++i) {              // load: coalesced 64-float rows
            int idx = tid + i * 256;
            int c = idx >> 6, j = idx & 63;
            tile[j * 33 + c] = din[((size_t)b * CDESC + c) * N + n0 + j];
        }
        __syncthreads();
#pragma unroll
        for (int i = 0; i < 8; ++i) {              // store: contiguous 32-float points
            int idx = tid + i * 256;
            int p = idx >> 5, c = idx & 31;
            dout[((size_t)b * N + n0 + p) * CDESC + c] = tile[p * 33 + c];
        }
    }
}

// K2: both stages' y/z-filter, 8 sub-threads per point (verified R6/R7).
__global__ __launch_bounds__(256) void pass2_both(
        const float* __restrict__ t16a, const float* __restrict__ t16b,
        const float* __restrict__ t8a,  const float* __restrict__ t8b,
        float4* __restrict__ ps0, float4* __restrict__ pt0,
        float4* __restrict__ ps1, float4* __restrict__ pt1) {
    int gid = blockIdx.x * 256 + threadIdx.x;
    if (blockIdx.x < 1024) {
        int sub = gid & 7, p = gid >> 3;
        int side = p >> 14, r = p & 16383;
        int b = r >> 12, n = r & 4095;
        int x = n & 15, y = (n >> 4) & 15, z = n >> 8;
        const float* t = side ? t16b : t16a;
        float wy[8]; int jy[8];
        float wys = 0.f, wzs = 0.f;
#pragma unroll
        for (int tt = 0; tt < 8; ++tt) {
            float w = 1.f - fabsf((float)tt - 3.5f) * 0.25f;
            int j = 4 * y - 2 + tt;
            bool v = (unsigned)j < 64u;
            wy[tt] = v ? w : 0.f; jy[tt] = v ? j : 0; wys += wy[tt];
            int jz = 4 * z - 2 + tt;
            if ((unsigned)jz < 64u) wzs += w;
        }
        float a0 = 0.f, a1 = 0.f, a2 = 0.f;
        {
            float wz = 1.f - fabsf((float)sub - 3.5f) * 0.25f;
            int jz = 4 * z - 2 + sub;
            if ((unsigned)jz < 64u) {
                const float* bz = t + (size_t)b * 196608 + jz * 1024 + x;
#pragma unroll
                for (int ty = 0; ty < 8; ++ty) {
                    float w = wz * wy[ty];
                    const float* pr = bz + jy[ty] * 16;
                    a0 = fmaf(w, pr[0],      a0);
                    a1 = fmaf(w, pr[65536],  a1);
                    a2 = fmaf(w, pr[131072], a2);
                }
            }
        }
#pragma unroll
        for (int m = 1; m < 8; m <<= 1) {
            a0 += __shfl_xor(a0, m, 64);
            a1 += __shfl_xor(a1, m, 64);
            a2 += __shfl_xor(a2, m, 64);
        }
        if (sub == 0) {
            float inv = 1.f / (wys * wzs);
            a0 *= inv; a1 *= inv; a2 *= inv;
            float4* pts = side ? pt0 : ps0;
            pts[b * N0 + n] = make_float4(a0, a1, a2, a0 * a0 + a1 * a1 + a2 * a2);
        }
    } else {
        int g = gid - 262144;
        int sub = g & 7, p = g >> 3;
        int side = p >> 11, r = p & 2047;
        int b = r >> 9, n = r & 511;
        int x = n & 7, y = (n >> 3) & 7, z = n >> 6;
        const float* t = side ? t8b : t8a;
        constexpr int CS = 64 * 64 * 8;
        float wy[16]; int jy[16];
        float wys = 0.f, wzs = 0.f;
#pragma unroll
        for (int tt = 0; tt < 16; ++tt) {
            float w = 1.f - fabsf((float)tt - 7.5f) * 0.125f;
            int j = 8 * y - 4 + tt;
            bool v = (unsigned)j < 64u;
            wy[tt] = v ? w : 0.f; jy[tt] = v ? j : 0; wys += wy[tt];
            int jz = 8 * z - 4 + tt;
            if ((unsigned)jz < 64u) wzs += w;
        }
        float a0 = 0.f, a1 = 0.f, a2 = 0.f;
#pragma unroll
        for (int k = 0; k < 2; ++k) {
            int tt = 2 * sub + k;
            float wz = 1.f - fabsf((float)tt - 7.5f) * 0.125f;
            int jz = 8 * z - 4 + tt;
            if ((unsigned)jz < 64u) {
                const float* bz = t + b * 3 * CS + jz * (64 * 8) + x;
#pragma unroll 1
                for (int ty = 0; ty < 16; ++ty) {
                    float w = wz * wy[ty];
                    const float* pr = bz + jy[ty] * 8;
                    a0 = fmaf(w, pr[0],      a0);
                    a1 = fmaf(w, pr[CS],     a1);
                    a2 = fmaf(w, pr[2 * CS], a2);
                }
            }
        }
#pragma unroll
        for (int m = 1; m < 8; m <<= 1) {
            a0 += __shfl_xor(a0, m, 64);
            a1 += __shfl_xor(a1, m, 64);
            a2 += __shfl_xor(a2, m, 64);
        }
        if (sub == 0) {
            float inv = 1.f / (wys * wzs);
            a0 *= inv; a1 *= inv; a2 *= inv;
            float4* pts = side ? pt1 : ps1;
            pts[b * N1 + n] = make_float4(a0, a1, a2, a0 * a0 + a1 * a1 + a2 * a2);
        }
    }
}

// cosine of two point-major 32-float descriptors (coalesced float4 reads)
__device__ __forceinline__ float cos_pm(const float* __restrict__ sT,
                                        const float* __restrict__ tT,
                                        size_t si, size_t ti) {
    const float4* s = (const float4*)(sT + si * CDESC);
    const float4* t = (const float4*)(tT + ti * CDESC);
    float num = 0.f, s2 = 0.f, t2 = 0.f;
#pragma unroll
    for (int c = 0; c < 8; ++c) {
        float4 a = s[c], g = t[c];
        num = fmaf(a.x, g.x, fmaf(a.y, g.y, fmaf(a.z, g.z, fmaf(a.w, g.w, num))));
        s2  = fmaf(a.x, a.x, fmaf(a.y, a.y, fmaf(a.z, a.z, fmaf(a.w, a.w, s2))));
        t2  = fmaf(g.x, g.x, fmaf(g.y, g.y, fmaf(g.z, g.z, fmaf(g.w, g.w, t2))));
    }
    return num / (fmaxf(sqrtf(s2), 1e-8f) * fmaxf(sqrtf(t2), 1e-8f));
}

// ======================= K3: argmin + cosine (R8 measured-best body) =======================
// blocks 0..255: stage-0, block = (b, 64-point tile). ALL 4096 targets staged to
//   64 KB dynamic LDS once; 4 waves split m into 4x1024 windows; lane = point.
//   Broadcast ds_read_b128 (conflict-free). Cross-wave combine via packed
//   (mono(d)<<32 | m) keys in LDS (reused buffer) == lexicographic (d,m) min
//   == jnp.argmin first-min. Then point-major coalesced cosine.
// blocks 256..263: stage-1 fused scan + cosine.
// Global 264-ticket on acc[2] finalizes out.
__global__ __launch_bounds__(256) void nn_cos_all(
        const float4* __restrict__ ps0, const float4* __restrict__ pt0,
        const float* __restrict__ sd0T, const float* __restrict__ td0T,
        const float4* __restrict__ ps1, const float4* __restrict__ pt1,
        const float* __restrict__ sd1T, const float* __restrict__ td1T,
        float* acc, float* __restrict__ out) {
    extern __shared__ __align__(16) char smraw[];  // 64 KB dynamic
    float4* sm = (float4*)smraw;
    const int tid = threadIdx.x;
    const int bx  = blockIdx.x;

    if (bx < 256) {
        int b = bx >> 6, ptile = bx & 63;
        const float4* tp = pt0 + b * N0;
        for (int i = tid; i < N0; i += 256) {      // stage all 4096 targets (64 KB)
            float4 q = tp[i];
            sm[i] = make_float4(-2.f * q.x, -2.f * q.y, -2.f * q.z, q.w);
        }
        __syncthreads();
        int w = tid >> 6, lane = tid & 63;
        int n = ptile * 64 + lane;
        float4 P = ps0[b * N0 + n];
        float best = FLT_MAX; int bi = 0;
        const int m0 = w * 1024;                   // this wave's m-window
#pragma unroll 16
        for (int k = 0; k < 1024; ++k) {
            float4 Q = sm[m0 + k];                 // broadcast, conflict-free
            float d = fmaf(P.x, Q.x, fmaf(P.y, Q.y, fmaf(P.z, Q.z, Q.w)));
            if (d < best) { best = d; bi = k; }    // ascending m: first-min
        }
        u64 key = ((u64)fbits_mono(best) << 32) | (unsigned)(m0 + bi);
        __syncthreads();                           // everyone done reading sm
        u64* keys = (u64*)smraw;                   // reuse LDS for combine
        keys[w * 64 + lane] = key;
        __syncthreads();
        if (tid < 64) {
            u64 k0 = keys[tid],       k1 = keys[tid + 64];
            u64 k2 = keys[tid + 128], k3 = keys[tid + 192];
            u64 ka = k0 < k1 ? k0 : k1;
            u64 kb = k2 < k3 ? k2 : k3;
            u64 kk = ka < kb ? ka : kb;            // windows ascending + u64 min
            int nearest = (int)(unsigned)(kk & 0xFFFFFFFFull);
            int n2 = ptile * 64 + tid;
            float cosv = cos_pm(sd0T, td0T, (size_t)b * N0 + n2,
                                (size_t)b * N0 + nearest);
            wave_reduce_atomic(cosv, acc + 0);
        }
    } else {
        int bb = bx - 256;
        int b = bb >> 1;
        const float4* tp = pt1 + b * N1;
        for (int i = tid; i < N1; i += 256) {
            float4 qq = tp[i];
            sm[i] = make_float4(-2.f * qq.x, -2.f * qq.y, -2.f * qq.z, qq.w);
        }
        __syncthreads();
        int n = (bb & 1) * 256 + tid;
        float4 P = ps1[b * N1 + n];
        float best = FLT_MAX; int bi = 0;
#pragma unroll 16
        for (int m = 0; m < N1; ++m) {
            float4 Q = sm[m];
            float d = fmaf(P.x, Q.x, fmaf(P.y, Q.y, fmaf(P.z, Q.z, Q.w)));
            if (d < best) { best = d; bi = m; }    // ascending m: first-min
        }
        float cosv = cos_pm(sd1T, td1T, (size_t)b * N1 + n, (size_t)b * N1 + bi);
        wave_reduce_atomic(cosv, acc + 1);
    }

    __syncthreads();                               // block's atomics all issued
    if (tid == 0) {
        __threadfence();
        unsigned old = atomicAdd((unsigned*)(acc + 2), 1u);
        if (old == 263u) {                         // last of 264 blocks
            float a0 = atomicAdd(acc + 0, 0.f);
            float a1 = atomicAdd(acc + 1, 0.f);
            out[0] = 1.f - 0.5f * (a0 * (1.f / 16384.f) + a1 * (1.f / 2048.f));
        }
    }
}

extern "C" void kernel_launch(void* const* d_in, const int* in_sizes, int n_in,
                              void* d_out, int out_size, void* d_ws, size_t ws_size,
                              hipStream_t stream) {
    const float* c_src = (const float*)d_in[0];   // [4,3,64,64,64]
    const float* c_tgt = (const float*)d_in[1];
    const float* sd0   = (const float*)d_in[2];   // [4,32,16,16,16]
    const float* td0   = (const float*)d_in[3];
    const float* sd1   = (const float*)d_in[4];   // [4,32,8,8,8]
    const float* td1   = (const float*)d_in[5];
    float* out = (float*)d_out;

    char* ws = (char*)d_ws;
    float* acc  = (float*)ws;                      // [0]=sum0 [1]=sum1 [2]=ticket
    float* t16a = (float*)(ws + 256);              // 786432 floats each
    float* t16b = t16a + 786432;
    float* t8a  = t16b + 786432;                   // 393216 floats each
    float* t8b  = t8a + 393216;
    float4* ps0 = (float4*)(t8b + 393216);         // 16384 float4
    float4* pt0 = ps0 + 16384;
    float4* ps1 = pt0 + 16384;                     // 2048 float4
    float4* pt1 = ps1 + 2048;
    float* sd0T = (float*)(pt1 + 2048);            // 524288 floats each
    float* td0T = sd0T + 524288;
    float* sd1T = td0T + 524288;                   // 65536 floats each
    float* td1T = sd1T + 65536;

    pass1_fused<<<dim3(1056, 2), 256, 0, stream>>>(c_src, c_tgt, sd0, td0, sd1, td1,
                                                   t16a, t16b, t8a, t8b,
                                                   sd0T, td0T, sd1T, td1T, acc);
    pass2_both<<<1152, 256, 0, stream>>>(t16a, t16b, t8a, t8b, ps0, pt0, ps1, pt1);
    nn_cos_all<<<264, 256, 65536, stream>>>(ps0, pt0, sd0T, td0T, ps1, pt1,
                                            sd1T, td1T, acc, out);
}